// Round 6
// baseline (3631.028 us; speedup 1.0000x reference)
//
#include <hip/hip_runtime.h>
#include <hip/hip_bf16.h>

#define T_LEN 2048
#define BATCH 32
#define HDIM 256
#define H3 768
#define EMBD 63
#define NSING 1024

// A/B fragment k-layout for mfma_f32_16x16x32_f16.
// LAYOUT_II=1: frag = concat of two 16x16x16-style frags:
//   elems 0-3 -> k = g*4+{0..3}, elems 4-7 -> k = 16+g*4+{0..3}  (g = lane>>4)
//   (evidence: ds_read_b64_tr_b16 geometry, learn_hip m156/m162)
// LAYOUT_II=0: contiguous k = g*8+{0..7} (fp8-x32 style). Flip if absmax fails.
#define LAYOUT_II 1

typedef _Float16 half8 __attribute__((ext_vector_type(8)));
typedef float f32x4 __attribute__((ext_vector_type(4)));

#define DPP_ADD(x, ctrl)                                                      \
  (x) += __builtin_bit_cast(                                                  \
      float, __builtin_amdgcn_update_dpp(                                     \
                 0, __builtin_bit_cast(int, (x)), (ctrl), 0xf, 0xf, true))

// P2[g][s][jj] (f16) = bi[g*256+jj] + sum_e embed[s,e] * Wi[(1+e)][g*256+jj]
__global__ __launch_bounds__(768) void precompute_P(
    const float* __restrict__ embed, const float* __restrict__ Wi,
    const float* __restrict__ bi, _Float16* __restrict__ P2) {
  const int s = blockIdx.x;
  const int jg = threadIdx.x;  // 0..767
  const int g = jg >> 8, jj = jg & 255;
  float acc = bi[jg];
  const float* er = embed + s * EMBD;
#pragma unroll
  for (int e = 0; e < EMBD; e++) acc += er[e] * Wi[(e + 1) * H3 + jg];
  P2[((size_t)g * NSING + s) * HDIM + jj] = (_Float16)acc;
}

// Pack Wh into MFMA B-fragments.
// Bp[((grp*96 + q)*64 + l)] (uint4), grp = dir*4 + wave, q = nt*8 + kt.
// Thread-lane l's fragment dword r holds f16 pair (Wh[k][j], Wh[k+1][j]) with
// j = wave*192 + nt*16 + (l&15), k per LAYOUT above.
__global__ __launch_bounds__(64) void pack_B(
    const float* __restrict__ Wh_f, const float* __restrict__ Wh_b,
    uint4* __restrict__ Bp) {
  const int bid = blockIdx.x;        // 0..767 = grp*96 + q
  const int grp = bid / 96, q = bid % 96;
  const int dir = grp >> 2, w = grp & 3;
  const int nt = q >> 3, kt = q & 7;
  const int l = threadIdx.x;
  const int g = l >> 4;
  const int j = w * 192 + nt * 16 + (l & 15);
  const float* Wh = dir ? Wh_b : Wh_f;
  unsigned int dw[4];
#pragma unroll
  for (int r = 0; r < 4; r++) {
#if LAYOUT_II
    const int k = kt * 32 + (r >= 2 ? 16 : 0) + g * 4 + (r & 1) * 2;
#else
    const int k = kt * 32 + g * 8 + r * 2;
#endif
    _Float16 lo = (_Float16)Wh[k * H3 + j];
    _Float16 hi = (_Float16)Wh[(k + 1) * H3 + j];
    dw[r] = (unsigned int)__builtin_bit_cast(unsigned short, lo) |
            ((unsigned int)__builtin_bit_cast(unsigned short, hi) << 16);
  }
  Bp[(size_t)bid * 64 + l] = make_uint4(dw[0], dw[1], dw[2], dw[3]);
}

// One workgroup per (dir, batch): 256 threads = 4 waves = 1 wave/SIMD
// (512 unified regs/wave). Recurrent matvec gh = h @ Wh via MFMA so the
// weight fragments live in AGPRs *natively* (MFMA reads AGPR/VGPR alike --
// no v_accvgpr_read copy tax, which is what capped rounds 1-5).
// Wave w owns N-tiles [12w,12w+12): 10 tiles in registers (320 dwords,
// allocator splits across AGPR+arch freely), 2 tiles staged in LDS (64 KB).
__global__ __attribute__((amdgpu_flat_work_group_size(256, 256),
                          amdgpu_waves_per_eu(1, 1))) void gru_scan(
    const float* __restrict__ dur, const int* __restrict__ sid,
    const uint4* __restrict__ Bp,
    const float* __restrict__ Wi_f, const float* __restrict__ Wi_b,
    const float* __restrict__ bhn_f, const float* __restrict__ bhn_b,
    const float* __restrict__ Wd,
    const _Float16* __restrict__ P2,  // [dir][g][s][256] f16
    float* __restrict__ pred) {       // [dir][b][t][4]
  const int b = blockIdx.x & 31;
  const int dir = blockIdx.x >> 5;
  const int tid = threadIdx.x;  // == output column j
  const int l = tid & 63;
  const int w = tid >> 6;
  const int g = l >> 4;

  const float* __restrict__ Wi = dir ? Wi_b : Wi_f;
  const float* __restrict__ bhn = dir ? bhn_b : bhn_f;
  const _Float16* __restrict__ Pd = P2 + (size_t)dir * 3 * NSING * HDIM;

  __shared__ __align__(16) _Float16 h_lds[HDIM];        // 512 B
  __shared__ float gh[H3];                              // 3 KB
  __shared__ uint4 blds[4][2][8][64];                   // 64 KB: 2 N-tiles/wave

  // ---- load B fragments: 80 uint4 in regs + 16 uint4 to LDS ----
  uint4 breg[80];
  {
    const uint4* bp = Bp + ((size_t)(dir * 4 + w) * 96) * 64 + l;
#pragma unroll
    for (int q = 0; q < 80; q++) breg[q] = bp[q * 64];
#pragma unroll
    for (int q = 80; q < 96; q++)
      blds[w][(q - 80) >> 3][(q - 80) & 7][l] = bp[q * 64];
  }

  const float wi0r = Wi[tid], wi0z = Wi[HDIM + tid], wi0n = Wi[2 * HDIM + tid];
  const float wd = Wd[dir * HDIM + tid];
  const float bhnj = bhn[tid];

  if (tid < 128) ((unsigned int*)h_lds)[tid] = 0u;
  float h_prev = 0.f;

  const float* durb = dur + b * T_LEN;
  const int* sidb = sid + b * T_LEN;
  float* predb = pred + ((size_t)(dir * BATCH + b)) * T_LEN * 4;

  // 1-deep prefetch of input-gate rows (every thread owns one j).
  float p_r, p_z, p_n;
  {
    const int s0 = sidb[dir ? (T_LEN - 1) : 0];
    p_r = (float)Pd[(0 * NSING + s0) * HDIM + tid];
    p_z = (float)Pd[(1 * NSING + s0) * HDIM + tid];
    p_n = (float)Pd[(2 * NSING + s0) * HDIM + tid];
  }
  __syncthreads();

#pragma unroll 1
  for (int t = 0; t < T_LEN; t++) {
    const int tt = dir ? (T_LEN - 1 - t) : t;
    const int tn = (t + 1 < T_LEN) ? (t + 1) : (T_LEN - 1);
    const int s1 = sidb[dir ? (T_LEN - 1 - tn) : tn];
    const float q_r = (float)Pd[(0 * NSING + s1) * HDIM + tid];
    const float q_z = (float)Pd[(1 * NSING + s1) * HDIM + tid];
    const float q_n = (float)Pd[(2 * NSING + s1) * HDIM + tid];
    const float d_c = durb[tt];

    // ---- A fragments: h broadcast (all lanes carry row-0 data -> all 16
    // output rows equal gh; we extract row 0) ----
    const char* hb = (const char*)h_lds;
    half8 a[8];
#pragma unroll
    for (int kt = 0; kt < 8; kt++) {
#if LAYOUT_II
      const uint2 lo = *(const uint2*)(hb + kt * 64 + g * 8);
      const uint2 hi = *(const uint2*)(hb + kt * 64 + 32 + g * 8);
      a[kt] = __builtin_bit_cast(half8, make_uint4(lo.x, lo.y, hi.x, hi.y));
#else
      a[kt] = __builtin_bit_cast(half8, *(const uint4*)(hb + kt * 64 + g * 16));
#endif
    }

    f32x4 acc[12];
#pragma unroll
    for (int nt = 0; nt < 12; nt++) acc[nt] = (f32x4){0.f, 0.f, 0.f, 0.f};
#pragma unroll
    for (int kt = 0; kt < 8; kt++) {
#pragma unroll
      for (int nt = 0; nt < 10; nt++)
        acc[nt] = __builtin_amdgcn_mfma_f32_16x16x32_f16(
            a[kt], __builtin_bit_cast(half8, breg[nt * 8 + kt]), acc[nt], 0, 0, 0);
      acc[10] = __builtin_amdgcn_mfma_f32_16x16x32_f16(
          a[kt], __builtin_bit_cast(half8, blds[w][0][kt][l]), acc[10], 0, 0, 0);
      acc[11] = __builtin_amdgcn_mfma_f32_16x16x32_f16(
          a[kt], __builtin_bit_cast(half8, blds[w][1][kt][l]), acc[11], 0, 0, 0);
    }

    // ---- extract row 0 (lanes 0-15, reg 0; verified C/D layout) ----
    if (l < 16) {
#pragma unroll
      for (int nt = 0; nt < 12; nt++) gh[w * 192 + nt * 16 + l] = acc[nt][0];
    }
    __syncthreads();  // B1: gh visible

    // ---- gates: thread j owns output column j ----
    const float ghr = gh[tid];
    const float ghz = gh[HDIM + tid];
    const float ghn = gh[2 * HDIM + tid];
    const float r = 1.f / (1.f + __expf(-(p_r + d_c * wi0r + ghr)));
    const float z = 1.f / (1.f + __expf(-(p_z + d_c * wi0z + ghz)));
    const float nin = p_n + d_c * wi0n + r * (ghn + bhnj);
    const float n = 1.f - 2.f / (1.f + __expf(2.f * nin));  // tanh, safe
    const float h_new = n + z * (h_prev - n);
    h_prev = h_new;
    ((unsigned short*)h_lds)[tid] =
        __builtin_bit_cast(unsigned short, (_Float16)h_new);

    // fused output head: per-wave DPP reduce of h_new * Wd[j]
    float pd = h_new * wd;
    DPP_ADD(pd, 0x111);  // row_shr:1
    DPP_ADD(pd, 0x112);  // row_shr:2
    DPP_ADD(pd, 0x114);  // row_shr:4
    DPP_ADD(pd, 0x118);  // row_shr:8
    DPP_ADD(pd, 0x142);  // row_bcast:15
    DPP_ADD(pd, 0x143);  // row_bcast:31 -> lane63 = wave total
    if (l == 63) predb[tt * 4 + w] = pd;

    p_r = q_r; p_z = q_z; p_n = q_n;
    __syncthreads();  // B2: h_lds update visible before next A-read
  }
}

__global__ __launch_bounds__(256) void combine(
    const float* __restrict__ pf, const float* __restrict__ pb,
    const float* __restrict__ bd, float* __restrict__ out) {
  const int i = blockIdx.x * 256 + threadIdx.x;  // i = b*2048 + t
  const float4 a = ((const float4*)pf)[i];
  const float4 c = ((const float4*)pb)[i];
  out[i] = (a.x + a.y + a.z + a.w) + (c.x + c.y + c.z + c.w) + bd[0];
}

extern "C" void kernel_launch(void* const* d_in, const int* in_sizes, int n_in,
                              void* d_out, int out_size, void* d_ws, size_t ws_size,
                              hipStream_t stream) {
  const float* dur = (const float*)d_in[0];
  const int* sid = (const int*)d_in[1];
  const float* embed = (const float*)d_in[2];
  const float* Wi_f = (const float*)d_in[3];
  const float* Wh_f = (const float*)d_in[4];
  const float* bi_f = (const float*)d_in[5];
  const float* bhn_f = (const float*)d_in[6];
  const float* Wi_b = (const float*)d_in[7];
  const float* Wh_b = (const float*)d_in[8];
  const float* bi_b = (const float*)d_in[9];
  const float* bhn_b = (const float*)d_in[10];
  const float* Wd = (const float*)d_in[11];
  const float* bd = (const float*)d_in[12];
  float* out = (float*)d_out;

  // ws (floats): pred 524288 | P2 (f16, 1572864 halves) 786432 | Bp 196608
  // dwords. Total 1507328 floats ~= 6.03 MB (same footprint as round 5).
  float* ws = (float*)d_ws;
  float* pred = ws;
  _Float16* P2 = (_Float16*)(ws + 524288);
  uint4* Bp = (uint4*)(ws + 524288 + 786432);

  hipLaunchKernelGGL(precompute_P, dim3(NSING), dim3(H3), 0, stream,
                     embed, Wi_f, bi_f, P2);
  hipLaunchKernelGGL(precompute_P, dim3(NSING), dim3(H3), 0, stream,
                     embed, Wi_b, bi_b, P2 + (size_t)3 * NSING * HDIM);
  hipLaunchKernelGGL(pack_B, dim3(768), dim3(64), 0, stream, Wh_f, Wh_b, Bp);
  hipLaunchKernelGGL(gru_scan, dim3(64), dim3(256), 0, stream,
                     dur, sid, Bp, Wi_f, Wi_b, bhn_f, bhn_b, Wd, P2, pred);
  hipLaunchKernelGGL(combine, dim3(256), dim3(256), 0, stream,
                     pred, pred + 262144, bd, out);
}

// Round 7
// 3069.313 us; speedup vs baseline: 1.1830x; 1.1830x over previous
//
#include <hip/hip_runtime.h>
#include <hip/hip_bf16.h>

#define T_LEN 2048
#define BATCH 32
#define HDIM 256
#define H3 768
#define EMBD 63
#define NSING 1024

typedef _Float16 half8 __attribute__((ext_vector_type(8)));
typedef _Float16 half4 __attribute__((ext_vector_type(4)));
typedef float f32x4 __attribute__((ext_vector_type(4)));

#define DPP_ADD(x, ctrl)                                                      \
  (x) += __builtin_bit_cast(                                                  \
      float, __builtin_amdgcn_update_dpp(                                     \
                 0, __builtin_bit_cast(int, (x)), (ctrl), 0xf, 0xf, true))

// P4[(s*256 + c)*4 + {0,1,2}] = (p_r, p_z, p_n) f16 for one direction.
__global__ __launch_bounds__(256) void precompute_P(
    const float* __restrict__ embed, const float* __restrict__ Wi,
    const float* __restrict__ bi, _Float16* __restrict__ P4) {
  const int s = blockIdx.x;
  const int c = threadIdx.x;
  float ar = bi[c], az = bi[HDIM + c], an = bi[2 * HDIM + c];
  const float* er = embed + s * EMBD;
#pragma unroll
  for (int e = 0; e < EMBD; e++) {
    const float ev = er[e];
    ar += ev * Wi[(e + 1) * H3 + c];
    az += ev * Wi[(e + 1) * H3 + HDIM + c];
    an += ev * Wi[(e + 1) * H3 + 2 * HDIM + c];
  }
  half4 h = {(_Float16)ar, (_Float16)az, (_Float16)an, (_Float16)0.f};
  *(half4*)(P4 + ((size_t)s * HDIM + c) * 4) = h;
}

// B-fragment pack, verified LAYOUT_II=1 k-mapping (round-6 absmax pass).
// bid = ((dir*4 + w)*12 + idx)*8 + kt ; idx = gate*4 + i ; nt = gate*16+w*4+i
__global__ __launch_bounds__(64) void pack_B(
    const float* __restrict__ Wh_f, const float* __restrict__ Wh_b,
    uint4* __restrict__ Bp) {
  const int bid = blockIdx.x;
  const int kt = bid & 7;
  const int idx = (bid >> 3) % 12;
  const int w = (bid / 96) & 3;
  const int d = bid / 384;
  const int l = threadIdx.x;
  const int g = l >> 4;
  const int gate = idx >> 2, i = idx & 3;
  const int nt = gate * 16 + w * 4 + i;
  const int j = nt * 16 + (l & 15);
  const float* Wh = d ? Wh_b : Wh_f;
  unsigned int dw[4];
#pragma unroll
  for (int r = 0; r < 4; r++) {
    const int k = kt * 32 + (r >= 2 ? 16 : 0) + g * 4 + (r & 1) * 2;
    _Float16 lo = (_Float16)Wh[k * H3 + j];
    _Float16 hi = (_Float16)Wh[(k + 1) * H3 + j];
    dw[r] = (unsigned int)__builtin_bit_cast(unsigned short, lo) |
            ((unsigned int)__builtin_bit_cast(unsigned short, hi) << 16);
  }
  Bp[(size_t)bid * 64 + l] = make_uint4(dw[0], dw[1], dw[2], dw[3]);
}

// One block per (dir,b): 256 threads = 4 waves = 1 wave/SIMD (512 unified
// regs/wave). Wave w owns cols [64w,64w+64) of ALL THREE gates:
// B = 96 tiles = 384 dwords/lane (AGPR+VGPR, MFMA reads both natively).
// Since all A-rows equal h, EVERY lane holds gh for col (tile, l&15) in
// acc[*][0] -> gates fully in-register (lane's col = w*64+l), no extract
// phase, single barrier/step with double-buffered permuted-h LDS.
__global__ __attribute__((amdgpu_flat_work_group_size(256, 256),
                          amdgpu_waves_per_eu(1, 1))) void gru_scan(
    const float* __restrict__ dur, const int* __restrict__ sid,
    const uint4* __restrict__ Bp,
    const float* __restrict__ Wi_f, const float* __restrict__ Wi_b,
    const float* __restrict__ bhn_f, const float* __restrict__ bhn_b,
    const float* __restrict__ Wd, const float* __restrict__ bd,
    const _Float16* __restrict__ P4,  // [dir][s][256][4] f16
    float* __restrict__ out) {        // [B][T] f32, pre-zeroed, atomicAdd
  const int b = blockIdx.x & 31;
  const int dir = blockIdx.x >> 5;
  const int tid = threadIdx.x;
  const int l = tid & 63;
  const int w = tid >> 6;
  const int g = l >> 4;      // A-fragment lane group AND my gate sub-tile i
  const int c = w * 64 + l;  // my gate/output column (0..255)

  __shared__ __align__(16) _Float16 hp[2][HDIM];  // permuted-h, double-buf

  // ---- B fragments: all 96 tiles resident (AGPR+VGPR) ----
  uint4 bfr[96];
  {
    const uint4* bp = Bp + ((size_t)(dir * 4 + w) * 96) * 64 + l;
#pragma unroll
    for (int q = 0; q < 96; q++) bfr[q] = bp[q * 64];
  }

  const float* __restrict__ Wi = dir ? Wi_b : Wi_f;
  const float wir = Wi[c], wiz = Wi[HDIM + c], win = Wi[2 * HDIM + c];
  const float bh = (dir ? bhn_b : bhn_f)[c];
  const float wd = Wd[dir * HDIM + c];
  const float bdv = bd[0];

  // permuted position of col c in the A-fragment order:
  // pos = (c>>5)*32 + ((c&15)>>2)*8 + ((c>>4)&1)*4 + (c&3)
  const int pos = ((c >> 5) << 5) + (((c & 15) >> 2) << 3) +
                  (((c >> 4) & 1) << 2) + (c & 3);
  char* const hbase = (char*)&hp[0][0];
  unsigned rb = g * 16;         // read base byte (buf 0)
  unsigned wb = 512 + pos * 2;  // write base byte (buf 1)

  if (tid < 128) ((unsigned int*)hbase)[tid] = 0u;  // zero hp[0]
  float hprev = 0.f;

  const float* durb = dur + b * T_LEN;
  const int* sidb = sid + b * T_LEN;
  const _Float16* Pdir = P4 + (size_t)dir * NSING * HDIM * 4;
  float* outb = out + (size_t)b * T_LEN;

  int s_cur = sidb[dir ? (T_LEN - 1) : 0];
  float d_cur = durb[dir ? (T_LEN - 1) : 0];
  __syncthreads();

#pragma unroll 1
  for (int t = 0; t < T_LEN; t++) {
    const int tt = dir ? (T_LEN - 1 - t) : t;
    const int tn = (t + 1 < T_LEN) ? (t + 1) : t;
    const int ttn = dir ? (T_LEN - 1 - tn) : tn;

    // P gather for this step (one b64/lane; latency hides under MFMA)
    const half4 pv = *(const half4*)(Pdir + ((size_t)s_cur * HDIM + c) * 4);
    // prefetch next-step scalars (uniform)
    const int s_nx = sidb[ttn];
    const float d_nx = durb[ttn];

    // A fragments: 8 broadcast ds_read_b128 from permuted h
    half8 a[8];
#pragma unroll
    for (int kt = 0; kt < 8; kt++)
      a[kt] = *(const half8*)(hbase + rb + kt * 64);

    f32x4 acc[12];
#pragma unroll
    for (int q = 0; q < 12; q++) acc[q] = (f32x4){0.f, 0.f, 0.f, 0.f};
#pragma unroll
    for (int kt = 0; kt < 8; kt++) {
#pragma unroll
      for (int q = 0; q < 12; q++)
        acc[q] = __builtin_amdgcn_mfma_f32_16x16x32_f16(
            a[kt], __builtin_bit_cast(half8, bfr[q * 8 + kt]), acc[q], 0, 0, 0);
      __builtin_amdgcn_sched_group_barrier(0x8, 12, 0);  // 12-way interleave
    }

    // ---- gates, fully in-register (my sub-tile i = g) ----
#define SEL(q0)                                                        \
  (g < 2 ? (g == 0 ? acc[q0][0] : acc[(q0) + 1][0])                    \
         : (g == 2 ? acc[(q0) + 2][0] : acc[(q0) + 3][0]))
    const float ghr = SEL(0);
    const float ghz = SEL(4);
    const float ghn = SEL(8);
#undef SEL
    const float xr = (float)pv[0] + d_cur * wir + ghr;
    const float xz = (float)pv[1] + d_cur * wiz + ghz;
    const float r = 1.f / (1.f + __expf(-xr));
    const float z = 1.f / (1.f + __expf(-xz));
    const float nin = (float)pv[2] + d_cur * win + r * (ghn + bh);
    const float n = 1.f - 2.f / (1.f + __expf(2.f * nin));  // tanh, safe
    const float h_new = n + z * (hprev - n);
    hprev = h_new;
    *(_Float16*)(hbase + wb) = (_Float16)h_new;

    // fused output head: full-wave DPP reduce, atomic into out
    float pd = h_new * wd;
    DPP_ADD(pd, 0x111);
    DPP_ADD(pd, 0x112);
    DPP_ADD(pd, 0x114);
    DPP_ADD(pd, 0x118);
    DPP_ADD(pd, 0x142);
    DPP_ADD(pd, 0x143);  // lane63 = wave total
    if (l == 63) {
      float v = pd;
      if (dir == 0 && w == 0) v += bdv;  // bias added exactly once per elem
      unsafeAtomicAdd(outb + tt, v);
    }

    s_cur = s_nx;
    d_cur = d_nx;
    __syncthreads();  // h writes visible; safe to swap buffers
    rb ^= 512;
    wb ^= 512;
  }
}

extern "C" void kernel_launch(void* const* d_in, const int* in_sizes, int n_in,
                              void* d_out, int out_size, void* d_ws, size_t ws_size,
                              hipStream_t stream) {
  const float* dur = (const float*)d_in[0];
  const int* sid = (const int*)d_in[1];
  const float* embed = (const float*)d_in[2];
  const float* Wi_f = (const float*)d_in[3];
  const float* Wh_f = (const float*)d_in[4];
  const float* bi_f = (const float*)d_in[5];
  const float* bhn_f = (const float*)d_in[6];
  const float* Wi_b = (const float*)d_in[7];
  const float* Wh_b = (const float*)d_in[8];
  const float* bi_b = (const float*)d_in[9];
  const float* bhn_b = (const float*)d_in[10];
  const float* Wd = (const float*)d_in[11];
  const float* bd = (const float*)d_in[12];
  float* out = (float*)d_out;

  // ws: P4 (2 dirs * 1024 * 256 * 4 f16 = 4 MB) | Bp (768*64 uint4 = 768 KB)
  _Float16* P4 = (_Float16*)d_ws;
  uint4* Bp = (uint4*)((char*)d_ws + (size_t)4 * 1024 * 1024);

  hipMemsetAsync(d_out, 0, (size_t)out_size * sizeof(float), stream);
  hipLaunchKernelGGL(precompute_P, dim3(NSING), dim3(256), 0, stream,
                     embed, Wi_f, bi_f, P4);
  hipLaunchKernelGGL(precompute_P, dim3(NSING), dim3(256), 0, stream,
                     embed, Wi_b, bi_b, P4 + (size_t)NSING * HDIM * 4);
  hipLaunchKernelGGL(pack_B, dim3(768), dim3(64), 0, stream, Wh_f, Wh_b, Bp);
  hipLaunchKernelGGL(gru_scan, dim3(64), dim3(256), 0, stream,
                     dur, sid, Bp, Wi_f, Wi_b, bhn_f, bhn_b, Wd, bd, P4, out);
}

// Round 8
// 2342.914 us; speedup vs baseline: 1.5498x; 1.3100x over previous
//
#include <hip/hip_runtime.h>
#include <hip/hip_bf16.h>

#define T_LEN 2048
#define BATCH 32
#define HDIM 256
#define H3 768
#define EMBD 63
#define NSING 1024

typedef _Float16 half8 __attribute__((ext_vector_type(8)));
typedef _Float16 half4 __attribute__((ext_vector_type(4)));
typedef float f32x4 __attribute__((ext_vector_type(4)));
typedef unsigned u32x4 __attribute__((ext_vector_type(4)));

#define DPP_ADD(x, ctrl)                                                      \
  (x) += __builtin_bit_cast(                                                  \
      float, __builtin_amdgcn_update_dpp(                                     \
                 0, __builtin_bit_cast(int, (x)), (ctrl), 0xf, 0xf, true))

// P4[(s*256 + c)*4 + {0,1,2}] = (p_r, p_z, p_n) f16 for one direction.
__global__ __launch_bounds__(256) void precompute_P(
    const float* __restrict__ embed, const float* __restrict__ Wi,
    const float* __restrict__ bi, _Float16* __restrict__ P4) {
  const int s = blockIdx.x;
  const int c = threadIdx.x;
  float ar = bi[c], az = bi[HDIM + c], an = bi[2 * HDIM + c];
  const float* er = embed + s * EMBD;
#pragma unroll
  for (int e = 0; e < EMBD; e++) {
    const float ev = er[e];
    ar += ev * Wi[(e + 1) * H3 + c];
    az += ev * Wi[(e + 1) * H3 + HDIM + c];
    an += ev * Wi[(e + 1) * H3 + 2 * HDIM + c];
  }
  half4 h = {(_Float16)ar, (_Float16)az, (_Float16)an, (_Float16)0.f};
  *(half4*)(P4 + ((size_t)s * HDIM + c) * 4) = h;
}

// B-fragment pack, verified LAYOUT_II k-mapping (rounds 6-7 absmax pass).
// bid = ((d*8 + w)*6 + q)*8 + kt ; gate = q>>1, s = q&1 ; nt = gate*16+2w+s
__global__ __launch_bounds__(64) void pack_B(
    const float* __restrict__ Wh_f, const float* __restrict__ Wh_b,
    uint4* __restrict__ Bp) {
  const int bid = blockIdx.x;  // 768 blocks
  const int kt = bid & 7;
  const int idx = bid >> 3;
  const int q = idx % 6;
  const int rest = idx / 6;
  const int w = rest & 7;
  const int d = rest >> 3;
  const int l = threadIdx.x;
  const int g = l >> 4;
  const int gate = q >> 1, s = q & 1;
  const int nt = gate * 16 + 2 * w + s;
  const int j = nt * 16 + (l & 15);
  const float* Wh = d ? Wh_b : Wh_f;
  unsigned int dw[4];
#pragma unroll
  for (int r = 0; r < 4; r++) {
    const int k = kt * 32 + (r >= 2 ? 16 : 0) + g * 4 + (r & 1) * 2;
    _Float16 lo = (_Float16)Wh[k * H3 + j];
    _Float16 hi = (_Float16)Wh[(k + 1) * H3 + j];
    dw[r] = (unsigned int)__builtin_bit_cast(unsigned short, lo) |
            ((unsigned int)__builtin_bit_cast(unsigned short, hi) << 16);
  }
  Bp[(size_t)bid * 64 + l] = make_uint4(dw[0], dw[1], dw[2], dw[3]);
}

// One block per (dir,b): 512 threads = 8 waves = 2 waves/SIMD (256 unified
// regs/wave). Wave w owns cols [32w, 32w+32): per gate 2 N-subtiles ->
// 48 B-tiles = 192 dwords, PINNED into arch VGPRs as 128-bit units so MFMA
// reads them copy-free (rounds 1-7 post-mortem: AGPR-homed operands cost a
// v_accvgpr_read per use, ~770 cy/step). acc (24 dw) -> AGPR, native for
// MFMA C/D. Lanes duplicate cols x2 (l and l^16 same col) -- harmless; dup
// lanes zeroed before the DPP output reduce, masked off for the h-write.
__global__ __attribute__((amdgpu_flat_work_group_size(512, 512),
                          amdgpu_waves_per_eu(2, 2))) void gru_scan(
    const float* __restrict__ dur, const int* __restrict__ sid,
    const uint4* __restrict__ Bp,
    const float* __restrict__ Wi_f, const float* __restrict__ Wi_b,
    const float* __restrict__ bhn_f, const float* __restrict__ bhn_b,
    const float* __restrict__ Wd, const float* __restrict__ bd,
    const _Float16* __restrict__ P4,  // [dir][s][256][4] f16
    float* __restrict__ out) {        // [B][T] f32, pre-zeroed, atomicAdd
  const int b = blockIdx.x & 31;
  const int dir = blockIdx.x >> 5;
  const int tid = threadIdx.x;
  const int l = tid & 63;
  const int w = tid >> 6;           // wave 0..7
  const int g = (l >> 4) & 3;       // A-fragment lane group
  const int s = l >> 5;             // my N-subtile (0/1) within the wave
  const int c = w * 32 + s * 16 + (l & 15);  // my gate/output column

  __shared__ __align__(16) _Float16 hp[2][HDIM];  // permuted-h, double-buf

  // ---- B fragments: 48 tiles, arch-VGPR-resident (128-bit pinned) ----
  u32x4 bfr[48];
  {
    const u32x4* bp = (const u32x4*)(Bp + ((size_t)(dir * 8 + w) * 48) * 64 + l);
#pragma unroll
    for (int i = 0; i < 48; i++) bfr[i] = bp[i * 64];
  }
#pragma unroll
  for (int i = 0; i < 48; i++) asm volatile("" : "+v"(bfr[i]));

  const float* __restrict__ Wi = dir ? Wi_b : Wi_f;
  const float wir = Wi[c], wiz = Wi[HDIM + c], win = Wi[2 * HDIM + c];
  const float bh = (dir ? bhn_b : bhn_f)[c];
  const float wd = Wd[dir * HDIM + c];
  const float bdv = bd[0];

  // permuted position of col c in the A-fragment k-order (verified r6/r7):
  const int pos = ((c >> 5) << 5) + (((c & 15) >> 2) << 3) +
                  (((c >> 4) & 1) << 2) + (c & 3);
  char* const hbase = (char*)&hp[0][0];
  unsigned rb = g * 16;         // read base byte (buf 0)
  unsigned wb = 512 + pos * 2;  // write base byte (buf 1)

  if (tid < 128) ((unsigned int*)hbase)[tid] = 0u;  // zero hp[0]
  float hprev = 0.f;

  const float* durb = dur + b * T_LEN;
  const int* sidb = sid + b * T_LEN;
  const _Float16* Pdir = P4 + (size_t)dir * NSING * HDIM * 4;
  float* outb = out + (size_t)b * T_LEN;

  int s_cur = sidb[dir ? (T_LEN - 1) : 0];
  float d_cur = durb[dir ? (T_LEN - 1) : 0];
  __syncthreads();

#pragma unroll 1
  for (int t = 0; t < T_LEN; t++) {
    const int tt = dir ? (T_LEN - 1 - t) : t;
    const int tn = (t + 1 < T_LEN) ? (t + 1) : t;
    const int ttn = dir ? (T_LEN - 1 - tn) : tn;

    // input-gate gather (consumed after MFMAs; latency hides under them)
    const half4 pv = *(const half4*)(Pdir + ((size_t)s_cur * HDIM + c) * 4);
    const int s_nx = sidb[ttn];      // uniform prefetch
    const float d_nx = durb[ttn];

    f32x4 acc[6];
#pragma unroll
    for (int q = 0; q < 6; q++) acc[q] = (f32x4){0.f, 0.f, 0.f, 0.f};

#pragma unroll
    for (int kt = 0; kt < 8; kt++) {
      const half8 a = *(const half8*)(hbase + rb + kt * 64);  // broadcast
#pragma unroll
      for (int q = 0; q < 6; q++)
        acc[q] = __builtin_amdgcn_mfma_f32_16x16x32_f16(
            a, __builtin_bit_cast(half8, bfr[q * 8 + kt]), acc[q], 0, 0, 0);
    }

    // all acc rows equal (broadcast A) -> reg 0 holds gh for col (tile,l&15)
    const float ghr = s ? acc[1][0] : acc[0][0];
    const float ghz = s ? acc[3][0] : acc[2][0];
    const float ghn = s ? acc[5][0] : acc[4][0];

    const float xr = (float)pv[0] + d_cur * wir + ghr;
    const float xz = (float)pv[1] + d_cur * wiz + ghz;
    const float r = 1.f / (1.f + __expf(-xr));
    const float z = 1.f / (1.f + __expf(-xz));
    const float nin = (float)pv[2] + d_cur * win + r * (ghn + bh);
    const float n = 1.f - 2.f / (1.f + __expf(2.f * nin));  // tanh, safe
    const float h_new = n + z * (hprev - n);
    hprev = h_new;

    if (!(l & 16))  // dedupe: one writer per col
      *(unsigned short*)(hbase + wb) =
          __builtin_bit_cast(unsigned short, (_Float16)h_new);

    // fused output head: zero dup lanes, DPP-reduce, one atomic per wave
    float pd = h_new * wd;
    if (l & 16) pd = 0.f;
    DPP_ADD(pd, 0x111);
    DPP_ADD(pd, 0x112);
    DPP_ADD(pd, 0x114);
    DPP_ADD(pd, 0x118);
    DPP_ADD(pd, 0x142);
    DPP_ADD(pd, 0x143);  // lane63 = wave total over its 32 cols
    if (l == 63) {
      float v = pd;
      if (dir == 0 && w == 0) v += bdv;  // bias added exactly once per elem
      unsafeAtomicAdd(outb + tt, v);
    }

    s_cur = s_nx;
    d_cur = d_nx;
    __syncthreads();  // h writes visible; swap buffers
    rb ^= 512;
    wb ^= 512;
  }
}

extern "C" void kernel_launch(void* const* d_in, const int* in_sizes, int n_in,
                              void* d_out, int out_size, void* d_ws, size_t ws_size,
                              hipStream_t stream) {
  const float* dur = (const float*)d_in[0];
  const int* sid = (const int*)d_in[1];
  const float* embed = (const float*)d_in[2];
  const float* Wi_f = (const float*)d_in[3];
  const float* Wh_f = (const float*)d_in[4];
  const float* bi_f = (const float*)d_in[5];
  const float* bhn_f = (const float*)d_in[6];
  const float* Wi_b = (const float*)d_in[7];
  const float* Wh_b = (const float*)d_in[8];
  const float* bi_b = (const float*)d_in[9];
  const float* bhn_b = (const float*)d_in[10];
  const float* Wd = (const float*)d_in[11];
  const float* bd = (const float*)d_in[12];
  float* out = (float*)d_out;

  // ws: P4 (2 dirs * 1024 * 256 * 4 f16 = 4 MB) | Bp (768*64 uint4 = 768 KB)
  _Float16* P4 = (_Float16*)d_ws;
  uint4* Bp = (uint4*)((char*)d_ws + (size_t)4 * 1024 * 1024);

  hipMemsetAsync(d_out, 0, (size_t)out_size * sizeof(float), stream);
  hipLaunchKernelGGL(precompute_P, dim3(NSING), dim3(256), 0, stream,
                     embed, Wi_f, bi_f, P4);
  hipLaunchKernelGGL(precompute_P, dim3(NSING), dim3(256), 0, stream,
                     embed, Wi_b, bi_b, P4 + (size_t)NSING * HDIM * 4);
  hipLaunchKernelGGL(pack_B, dim3(768), dim3(64), 0, stream, Wh_f, Wh_b, Bp);
  hipLaunchKernelGGL(gru_scan, dim3(64), dim3(512), 0, stream,
                     dur, sid, Bp, Wi_f, Wi_b, bhn_f, bhn_b, Wd, bd, P4, out);
}